// Round 9
// baseline (401.491 us; speedup 1.0000x reference)
//
#include <hip/hip_runtime.h>
#include <math.h>

typedef float v2f __attribute__((ext_vector_type(2)));
typedef float v4f __attribute__((ext_vector_type(4)));

__device__ __forceinline__ float hsum(v2f a) { return a.x + a.y; }
__device__ __forceinline__ float rsq_(float x) { return __builtin_amdgcn_rsqf(fmaxf(x, 1e-16f)); }
__device__ __forceinline__ float rcp_(float x) { return __builtin_amdgcn_rcpf(x); }

__device__ __forceinline__ void pk4(v2f& acc, v4f a, v4f b) {
    acc += a.xy * b.xy;
    acc += a.zw * b.zw;
}

// ============================ Kernel 1: dense phase ============================
// One wave per batch. lane = output dim. Stages into d_out's per-batch S slot:
//   out[b*2048 + k*64 + d]   = new_fact[k][d]
//   out[b*2048 + 1024 + l]   = fire[16] | dconf[16] | 1/||cand||[16]
//   out[B*2048 + b]          = best_derived_conf
__global__ __launch_bounds__(128, 4)
void dense_kernel(const float* __restrict__ content,   // [B,16,64]
                  const float* __restrict__ types,     // [B,16,3]
                  const float* __restrict__ conf,      // [B,16]
                  const float* __restrict__ W_ante,    // [64,64]
                  const float* __restrict__ W_cons,    // [64,128]
                  const float* __restrict__ lft,       // [1]
                  float* __restrict__ out, int B)
{
    const int l = threadIdx.x & 63;
    const int w = threadIdx.x >> 6;
    const int b = blockIdx.x * 2 + w;
    if (b >= B) return;

    __shared__ float s_cont[2][16*68];   // content -> later new_fact
    __shared__ float s_scr [2][16*68];   // ante -> later matched
    __shared__ float s_ms  [2][16*20];   // match_scores
    __shared__ float s_sm  [2][96];      // conf@0 pf@16 pr@32 rcn@48 ran@64
    float* cont = s_cont[w];
    float* scr  = s_scr[w];
    float* ms   = s_ms[w];
    float* sm   = s_sm[w];

    const float thr = expf(lft[0]);

    // load content (regs + LDS), conf/types
    float c[16];
    const float* cb = content + ((size_t)b << 10);
    #pragma unroll
    for (int k = 0; k < 16; k++) {
        float v = cb[(k << 6) + l];
        c[k] = v;
        cont[k*68 + l] = v;
    }
    if (l < 16) {
        sm[0  + l] = conf[((size_t)b << 4) + l];
        sm[16 + l] = types[(((size_t)b << 4) + l)*3 + 0];   // p_fact
        sm[32 + l] = types[(((size_t)b << 4) + l)*3 + 1];   // p_rule
    }

    // content inverse norms -> sm[48+k]
    {
        const int k = l & 15, q = l >> 4;
        const v4f* row = (const v4f*)&cont[k*68 + q*16];
        v2f s2 = {0.f, 0.f};
        #pragma unroll
        for (int i = 0; i < 4; i++) { v4f v = row[i]; pk4(s2, v, v); }
        float s = hsum(s2);
        s += __shfl_xor(s, 16, 64);
        s += __shfl_xor(s, 32, 64);
        if (l < 16) sm[48 + l] = rsq_(s);
    }

    // ante = content @ W_ante^T (W row resident in regs as v2f pairs)
    v2f wA[32];
    {
        const v4f* wr = (const v4f*)(W_ante + ((size_t)l << 6));
        #pragma unroll
        for (int i = 0; i < 16; i++) { v4f v = wr[i]; wA[2*i] = v.xy; wA[2*i+1] = v.zw; }
    }
    #pragma unroll
    for (int k = 0; k < 16; k++) {
        const v4f* cr = (const v4f*)&cont[k*68];
        v2f a = {0.f, 0.f};
        #pragma unroll
        for (int i = 0; i < 16; i++) { v4f v = cr[i]; a += v.xy*wA[2*i]; a += v.zw*wA[2*i+1]; }
        scr[k*68 + l] = hsum(a);
    }

    // ante inverse norms -> sm[64+k]
    {
        const int k = l & 15, q = l >> 4;
        const v4f* row = (const v4f*)&scr[k*68 + q*16];
        v2f s2 = {0.f, 0.f};
        #pragma unroll
        for (int i = 0; i < 4; i++) { v4f v = row[i]; pk4(s2, v, v); }
        float s = hsum(s2);
        s += __shfl_xor(s, 16, 64);
        s += __shfl_xor(s, 32, 64);
        if (l < 16) sm[64 + l] = rsq_(s);
    }

    // dots + match_scores: lane -> (k = l&15, 4 j's); sim = dot * ran * rcn * pf
    {
        const int k = l & 15, jg4 = (l >> 4) * 4;
        const v4f* ar = (const v4f*)&scr[k*68];
        const v4f* c0 = (const v4f*)&cont[(jg4+0)*68];
        const v4f* c1 = (const v4f*)&cont[(jg4+1)*68];
        const v4f* c2 = (const v4f*)&cont[(jg4+2)*68];
        const v4f* c3 = (const v4f*)&cont[(jg4+3)*68];
        v2f d0 = {0,0}, d1 = {0,0}, d2 = {0,0}, d3 = {0,0};
        #pragma unroll
        for (int i = 0; i < 16; i++) {
            v4f a = ar[i];
            v4f x0 = c0[i]; d0 += a.xy*x0.xy; d0 += a.zw*x0.zw;
            v4f x1 = c1[i]; d1 += a.xy*x1.xy; d1 += a.zw*x1.zw;
            v4f x2 = c2[i]; d2 += a.xy*x2.xy; d2 += a.zw*x2.zw;
            v4f x3 = c3[i]; d3 += a.xy*x3.xy; d3 += a.zw*x3.zw;
        }
        const float ra = sm[64 + k];
        v4f res;
        res.x = hsum(d0) * ra * sm[48 + jg4+0] * sm[16 + jg4+0];
        res.y = hsum(d1) * ra * sm[48 + jg4+1] * sm[16 + jg4+1];
        res.z = hsum(d2) * ra * sm[48 + jg4+2] * sm[16 + jg4+2];
        res.w = hsum(d3) * ra * sm[48 + jg4+3] * sm[16 + jg4+3];
        *(v4f*)&ms[k*20 + jg4] = res;
    }

    // match_strength -> fire / dconf (lanes 0..15) -> staging + tail
    float dc_l = 0.f;
    if (l < 16) {
        const v4f* mr = (const v4f*)&ms[l*20];
        const v4f* cf = (const v4f*)&sm[0];
        v2f st = {0.f, 0.f};
        #pragma unroll
        for (int i = 0; i < 4; i++) { v4f m4 = mr[i]; v4f f4 = cf[i]; st += m4.xy*f4.xy; st += m4.zw*f4.zw; }
        float str = hsum(st);
        float fire = sm[32 + l] * rcp_(1.0f + __expf(-(str - thr) * 2.0f));
        float dcf  = fire * sm[0 + l];
        out[((size_t)b << 11) + 1024 + l] = fire;
        out[((size_t)b << 11) + 1040 + l] = dcf;
        dc_l = dcf;
    }
    {
        float mv = dc_l;
        mv = fmaxf(mv, __shfl_xor(mv, 1, 64));
        mv = fmaxf(mv, __shfl_xor(mv, 2, 64));
        mv = fmaxf(mv, __shfl_xor(mv, 4, 64));
        mv = fmaxf(mv, __shfl_xor(mv, 8, 64));
        if (l == 0) out[((size_t)B << 11) + b] = mv;
    }

    // matched[k][d] = sum_j ms[k][j] * content[j][d]  (from regs c[])
    float mt[16];
    #pragma unroll
    for (int k = 0; k < 16; k++) {
        const v4f* mr = (const v4f*)&ms[k*20];
        v2f m2 = {0.f, 0.f};
        #pragma unroll
        for (int i = 0; i < 4; i++) {
            v4f m4 = mr[i];
            v2f clo = {c[4*i+0], c[4*i+1]};
            v2f chi = {c[4*i+2], c[4*i+3]};
            m2 += m4.xy*clo; m2 += m4.zw*chi;
        }
        mt[k] = hsum(m2);
    }
    #pragma unroll
    for (int k = 0; k < 16; k++) scr[k*68 + l] = mt[k];   // ante dead -> matched

    // new_fact = content @ W1^T + matched @ W2^T
    float nf[16];
    {
        const v4f* wr = (const v4f*)(W_cons + ((size_t)l << 7));
        #pragma unroll
        for (int i = 0; i < 16; i++) { v4f v = wr[i]; wA[2*i] = v.xy; wA[2*i+1] = v.zw; }
    }
    #pragma unroll
    for (int k = 0; k < 16; k++) {
        const v4f* cr = (const v4f*)&cont[k*68];
        v2f a = {0.f, 0.f};
        #pragma unroll
        for (int i = 0; i < 16; i++) { v4f v = cr[i]; a += v.xy*wA[2*i]; a += v.zw*wA[2*i+1]; }
        nf[k] = hsum(a);
    }
    {
        const v4f* wr = (const v4f*)(W_cons + ((size_t)l << 7) + 64);
        #pragma unroll
        for (int i = 0; i < 16; i++) { v4f v = wr[i]; wA[2*i] = v.xy; wA[2*i+1] = v.zw; }
    }
    #pragma unroll
    for (int k = 0; k < 16; k++) {
        const v4f* mr = (const v4f*)&scr[k*68];
        v2f a = {0.f, 0.f};
        #pragma unroll
        for (int i = 0; i < 16; i++) { v4f v = mr[i]; a += v.xy*wA[2*i]; a += v.zw*wA[2*i+1]; }
        nf[k] += hsum(a);
    }

    // nf -> LDS (for norms) + global staging
    #pragma unroll
    for (int k = 0; k < 16; k++) {
        cont[k*68 + l] = nf[k];
        out[((size_t)b << 11) + (k << 6) + l] = nf[k];
    }

    // 1/||cand|| -> staging
    {
        const int k = l & 15, q = l >> 4;
        const v4f* row = (const v4f*)&cont[k*68 + q*16];
        v2f s2 = {0.f, 0.f};
        #pragma unroll
        for (int i = 0; i < 4; i++) { v4f v = row[i]; pk4(s2, v, v); }
        float s = hsum(s2);
        s += __shfl_xor(s, 16, 64);
        s += __shfl_xor(s, 32, 64);
        if (l < 16) out[((size_t)b << 11) + 1056 + l] = rsq_(s);
    }
}

// ============================ Kernel 2: sequential scan ============================
// TWO batches per wave (branchless dual chains, shared W1 stream), 4 waves/block.
// S register-resident in (m = l&31, h = l>>5) lane layout. k-loop = LDS + regs only.
__global__ __launch_bounds__(256, 2)
void scan_kernel(const float* __restrict__ Sg,      // [B,32,64]
                 const float* __restrict__ W_gw,    // [64,128]
                 const float* __restrict__ W_gb,    // [64]
                 float* __restrict__ out, int B)
{
    const int t = threadIdx.x;
    const int l = t & 63;
    const int w = t >> 6;
    const int c0 = (w << 1), c1 = c0 + 1;        // chain slots in block
    const int b0r = (blockIdx.x << 3) + c0;
    const int b1r = (blockIdx.x << 3) + c1;
    const int b0 = (b0r < B) ? b0r : 0;          // clamp for loads
    const int b1 = (b1r < B) ? b1r : 0;

    __shared__ v4f            w1v[1024];         // block-shared W1, transposed v4f
    __shared__ float          snf_  [8][16*64];  // new_fact rows per chain
    __shared__ unsigned short gcB_  [8][16*64];  // bf16 gamma cand-half
    __shared__ float          smeta_[8][48];     // fire | dconf | 1/||cand||
    __shared__ float          bsb_  [8][64];     // best-slot row per chain
    __shared__ float          ncb_  [8][64];     // new_content per chain
    float* snfA = snf_[c0];            float* snfB = snf_[c1];
    unsigned short* gcA = gcB_[c0];    unsigned short* gcB = gcB_[c1];
    float* smA  = smeta_[c0];          float* smB  = smeta_[c1];
    float* bsbA = bsb_[c0];            float* bsbB = bsb_[c1];
    float* ncbA = ncb_[c0];            float* ncbB = ncb_[c1];

    const int m = l & 31, h = l >> 5;

    // -------- block-cooperative W1 -> LDS (transposed v4f layout) --------
    {
        const int q = t >> 6;
        #pragma unroll
        for (int j = 0; j < 4; j++) {
            const int i = q*4 + j;
            w1v[i*64 + l] = *(const v4f*)&W_gw[(size_t)l*128 + i*4];
        }
    }

    // -------- per-chain staging --------
    if (l < 48) {
        smA[l] = out[((size_t)b0 << 11) + 1024 + l];
        smB[l] = out[((size_t)b1 << 11) + 1024 + l];
    }
    const float* nfb0 = out + ((size_t)b0 << 11);
    const float* nfb1 = out + ((size_t)b1 << 11);
    #pragma unroll
    for (int i = 0; i < 4; i++) {
        *(v4f*)&snfA[i*256 + l*4] = *(const v4f*)&nfb0[i*256 + l*4];
        *(v4f*)&snfB[i*256 + l*4] = *(const v4f*)&nfb1[i*256 + l*4];
    }

    v2f SregA[16], SregB[16];
    {
        const float* s0 = Sg + ((size_t)b0 << 11) + (m << 6) + (h << 5);
        const float* s1 = Sg + ((size_t)b1 << 11) + (m << 6) + (h << 5);
        #pragma unroll
        for (int i = 0; i < 8; i++) {
            v4f v0 = *(const v4f*)&s0[i*4];
            v4f v1 = *(const v4f*)&s1[i*4];
            SregA[2*i] = v0.xy; SregA[2*i+1] = v0.zw;
            SregB[2*i] = v1.xy; SregB[2*i+1] = v1.zw;
        }
    }

    // gc[k][l] = cand_k . W2[l]  for both chains (wB loaded once, transient)
    {
        v2f wB[32];
        const v4f* w2 = (const v4f*)(W_gw + ((size_t)l << 7) + 64);
        #pragma unroll
        for (int i = 0; i < 16; i++) { v4f v = w2[i]; wB[2*i] = v.xy; wB[2*i+1] = v.zw; }
        #pragma unroll
        for (int k = 0; k < 16; k++) {
            const v4f* crA = (const v4f*)&snfA[k << 6];
            const v4f* crB = (const v4f*)&snfB[k << 6];
            v2f aA = {0.f, 0.f}, aB = {0.f, 0.f};
            #pragma unroll
            for (int i = 0; i < 16; i++) {
                v4f vA = crA[i]; aA += vA.xy*wB[2*i]; aA += vA.zw*wB[2*i+1];
                v4f vB = crB[i]; aB += vB.xy*wB[2*i]; aB += vB.zw*wB[2*i+1];
            }
            gcA[(k << 6) + l] = (unsigned short)((__float_as_uint(hsum(aA)) + 0x8000u) >> 16);
            gcB[(k << 6) + l] = (unsigned short)((__float_as_uint(hsum(aB)) + 0x8000u) >> 16);
        }
    }

    __syncthreads();          // w1v visible to all waves

    const float gb = W_gb[l];

    // ---------------- dual-chain scan: branchless, straight-line ----------------
    #pragma unroll 1
    for (int k = 0; k < 16; k++) {
        const float fireA = smA[k],      fireB = smB[k];
        const float dckA  = smA[16 + k], dckB  = smB[16 + k];
        const float rncA  = smA[32 + k], rncB  = smB[32 + k];
        const float gckA  = __uint_as_float((unsigned)gcA[(k << 6) + l] << 16);
        const float gckB  = __uint_as_float((unsigned)gcB[(k << 6) + l] << 16);
        const float cdA   = snfA[(k << 6) + l];
        const float cdB   = snfB[(k << 6) + l];

        // dot + norm, both chains (independent -> ILP x2)
        v2f dA = {0,0}, nA = {0,0}, dB = {0,0}, nB = {0,0};
        {
            const v4f* crA = (const v4f*)&snfA[(k << 6) + (h << 5)];
            const v4f* crB = (const v4f*)&snfB[(k << 6) + (h << 5)];
            #pragma unroll
            for (int i = 0; i < 8; i++) {
                v4f cA = crA[i], cB = crB[i];
                dA += SregA[2*i]*cA.xy;        dA += SregA[2*i+1]*cA.zw;
                nA += SregA[2*i]*SregA[2*i];   nA += SregA[2*i+1]*SregA[2*i+1];
                dB += SregB[2*i]*cB.xy;        dB += SregB[2*i+1]*cB.zw;
                nB += SregB[2*i]*SregB[2*i];   nB += SregB[2*i+1]*SregB[2*i+1];
            }
        }
        float dtA = hsum(dA), nnA = hsum(nA);
        float dtB = hsum(dB), nnB = hsum(nB);
        dtA += __shfl_xor(dtA, 32, 64);  nnA += __shfl_xor(nnA, 32, 64);
        dtB += __shfl_xor(dtB, 32, 64);  nnB += __shfl_xor(nnB, 32, 64);
        const float scA = dtA * rsq_(nnA) * rncA;
        const float scB = dtB * rsq_(nnB) * rncB;

        // softmax weight + sum; argmax -- dual interleaved shfl chains
        const float eA = __expf(4.0f * scA);
        const float eB = __expf(4.0f * scB);
        float seA = eA, seB = eB, mxA = scA, mxB = scB;
        seA += __shfl_xor(seA, 1, 64);   seB += __shfl_xor(seB, 1, 64);
        mxA = fmaxf(mxA, __shfl_xor(mxA, 1, 64));  mxB = fmaxf(mxB, __shfl_xor(mxB, 1, 64));
        seA += __shfl_xor(seA, 2, 64);   seB += __shfl_xor(seB, 2, 64);
        mxA = fmaxf(mxA, __shfl_xor(mxA, 2, 64));  mxB = fmaxf(mxB, __shfl_xor(mxB, 2, 64));
        seA += __shfl_xor(seA, 4, 64);   seB += __shfl_xor(seB, 4, 64);
        mxA = fmaxf(mxA, __shfl_xor(mxA, 4, 64));  mxB = fmaxf(mxB, __shfl_xor(mxB, 4, 64));
        seA += __shfl_xor(seA, 8, 64);   seB += __shfl_xor(seB, 8, 64);
        mxA = fmaxf(mxA, __shfl_xor(mxA, 8, 64));  mxB = fmaxf(mxB, __shfl_xor(mxB, 8, 64));
        seA += __shfl_xor(seA, 16, 64);  seB += __shfl_xor(seB, 16, 64);
        mxA = fmaxf(mxA, __shfl_xor(mxA, 16, 64)); mxB = fmaxf(mxB, __shfl_xor(mxB, 16, 64));
        const int bestA = __ffsll(__ballot(scA == mxA) & 0xffffffffULL) - 1;
        const int bestB = __ffsll(__ballot(scB == mxB) & 0xffffffffULL) - 1;

        // branchless fire: wm = 0 when not fired -> S unchanged exactly
        const float wmA = (fireA > 0.1f) ? dckA * eA * rcp_(seA) : 0.0f;
        const float wmB = (fireB > 0.1f) ? dckB * eB * rcp_(seB) : 0.0f;

        // best-slot rows -> bsb (owning lanes write)
        if (m == bestA) {
            #pragma unroll
            for (int j = 0; j < 8; j++) {
                v4f v = { SregA[2*j].x, SregA[2*j].y, SregA[2*j+1].x, SregA[2*j+1].y };
                *(v4f*)&bsbA[(h << 5) + j*4] = v;
            }
        }
        if (m == bestB) {
            #pragma unroll
            for (int j = 0; j < 8; j++) {
                v4f v = { SregB[2*j].x, SregB[2*j].y, SregB[2*j+1].x, SregB[2*j+1].y };
                *(v4f*)&bsbB[(h << 5) + j*4] = v;
            }
        }

        // gamma dots: ONE shared W1 row read feeds both chains
        v2f g2A = {0,0}, g2B = {0,0};
        {
            const v4f* wrow = &w1v[l];
            #pragma unroll
            for (int i = 0; i < 16; i++) {
                v4f wv = wrow[i*64];                     // per-lane, conflict-free
                v4f bA = *(const v4f*)&bsbA[i*4];        // broadcast
                v4f bB = *(const v4f*)&bsbB[i*4];        // broadcast
                g2A += bA.xy*wv.xy; g2A += bA.zw*wv.zw;
                g2B += bB.xy*wv.xy; g2B += bB.zw*wv.zw;
            }
        }
        const float gA = gb + gckA + hsum(g2A);
        const float gB = gb + gckB + hsum(g2B);
        const float gammaA = rcp_(1.0f + __expf(-gA));
        const float gammaB = rcp_(1.0f + __expf(-gB));
        ncbA[l] = gammaA*cdA + (1.0f - gammaA)*bsbA[l];
        ncbB[l] = gammaB*cdB + (1.0f - gammaB)*bsbB[l];

        // updates
        const v2f wA2 = {wmA, wmA}, wB2 = {wmB, wmB};
        {
            const v4f* nrA = (const v4f*)&ncbA[h << 5];
            const v4f* nrB = (const v4f*)&ncbB[h << 5];
            #pragma unroll
            for (int i = 0; i < 8; i++) {
                v4f nA4 = nrA[i], nB4 = nrB[i];
                SregA[2*i]   += wA2 * (nA4.xy - SregA[2*i]);
                SregA[2*i+1] += wA2 * (nA4.zw - SregA[2*i+1]);
                SregB[2*i]   += wB2 * (nB4.xy - SregB[2*i]);
                SregB[2*i+1] += wB2 * (nB4.zw - SregB[2*i+1]);
            }
        }
    }

    // store S_new (skip invalid chains)
    if (b0r < B) {
        float* ob = out + ((size_t)b0r << 11) + (m << 6) + (h << 5);
        #pragma unroll
        for (int j = 0; j < 8; j++) {
            v4f v = { SregA[2*j].x, SregA[2*j].y, SregA[2*j+1].x, SregA[2*j+1].y };
            *(v4f*)&ob[j*4] = v;
        }
    }
    if (b1r < B) {
        float* ob = out + ((size_t)b1r << 11) + (m << 6) + (h << 5);
        #pragma unroll
        for (int j = 0; j < 8; j++) {
            v4f v = { SregB[2*j].x, SregB[2*j].y, SregB[2*j+1].x, SregB[2*j+1].y };
            *(v4f*)&ob[j*4] = v;
        }
    }
}

extern "C" void kernel_launch(void* const* d_in, const int* in_sizes, int n_in,
                              void* d_out, int out_size, void* d_ws, size_t ws_size,
                              hipStream_t stream) {
    const float* content = (const float*)d_in[0];
    const float* types   = (const float*)d_in[1];
    const float* conf    = (const float*)d_in[2];
    const float* S       = (const float*)d_in[3];
    const float* W_ante  = (const float*)d_in[4];
    const float* W_cons  = (const float*)d_in[5];
    const float* W_gw    = (const float*)d_in[6];
    const float* W_gb    = (const float*)d_in[7];
    const float* lft     = (const float*)d_in[8];

    const int B = in_sizes[0] / 1024;

    hipLaunchKernelGGL(dense_kernel, dim3((B + 1) / 2), dim3(128), 0, stream,
                       content, types, conf, W_ante, W_cons, lft, (float*)d_out, B);
    hipLaunchKernelGGL(scan_kernel, dim3((B + 7) / 8), dim3(256), 0, stream,
                       S, W_gw, W_gb, (float*)d_out, B);
}

// Round 11
// 325.227 us; speedup vs baseline: 1.2345x; 1.2345x over previous
//
#include <hip/hip_runtime.h>
#include <math.h>

typedef float v2f __attribute__((ext_vector_type(2)));
typedef float v4f __attribute__((ext_vector_type(4)));

__device__ __forceinline__ float hsum(v2f a) { return a.x + a.y; }
__device__ __forceinline__ float rsq_(float x) { return __builtin_amdgcn_rsqf(fmaxf(x, 1e-16f)); }
__device__ __forceinline__ float rcp_(float x) { return __builtin_amdgcn_rcpf(x); }

__device__ __forceinline__ void pk4(v2f& acc, v4f a, v4f b) {
    acc += a.xy * b.xy;
    acc += a.zw * b.zw;
}

// ---- DPP wave-wide reductions (VALU, no LDS pipe). CTRL must be a template
// constant: __builtin_amdgcn_update_dpp requires an immediate operand.
template<int CTRL>
__device__ __forceinline__ float dpp_add_(float x) {
    int r = __builtin_amdgcn_update_dpp(0, __float_as_int(x), CTRL, 0xF, 0xF, true);
    return x + __int_as_float(r);
}
template<int CTRL>
__device__ __forceinline__ float dpp_max_(float x) {
    int r = __builtin_amdgcn_update_dpp(__float_as_int(x), __float_as_int(x), CTRL, 0xF, 0xF, false);
    return fmaxf(x, __int_as_float(r));
}
// full-64-lane sum, result uniform (readlane 63)
__device__ __forceinline__ float dpp_sum64(float x) {
    x = dpp_add_<0x111>(x);   // row_shr:1
    x = dpp_add_<0x112>(x);   // row_shr:2
    x = dpp_add_<0x114>(x);   // row_shr:4
    x = dpp_add_<0x118>(x);   // row_shr:8
    x = dpp_add_<0x142>(x);   // row_bcast15
    x = dpp_add_<0x143>(x);   // row_bcast31
    return __int_as_float(__builtin_amdgcn_readlane(__float_as_int(x), 63));
}
// full-64-lane max, result uniform
__device__ __forceinline__ float dpp_max64(float x) {
    x = dpp_max_<0x111>(x);
    x = dpp_max_<0x112>(x);
    x = dpp_max_<0x114>(x);
    x = dpp_max_<0x118>(x);
    x = dpp_max_<0x142>(x);
    x = dpp_max_<0x143>(x);
    return __int_as_float(__builtin_amdgcn_readlane(__float_as_int(x), 63));
}

// ============================ Kernel 1: dense phase ============================
// One wave per batch. lane = output dim. Stages into d_out's per-batch S slot:
//   out[b*2048 + k*64 + d]   = new_fact[k][d]
//   out[b*2048 + 1024 + l]   = fire[16] | dconf[16] | 1/||cand||[16]
//   out[B*2048 + b]          = best_derived_conf
__global__ __launch_bounds__(128, 4)
void dense_kernel(const float* __restrict__ content,   // [B,16,64]
                  const float* __restrict__ types,     // [B,16,3]
                  const float* __restrict__ conf,      // [B,16]
                  const float* __restrict__ W_ante,    // [64,64]
                  const float* __restrict__ W_cons,    // [64,128]
                  const float* __restrict__ lft,       // [1]
                  float* __restrict__ out, int B)
{
    const int l = threadIdx.x & 63;
    const int w = threadIdx.x >> 6;
    const int b = blockIdx.x * 2 + w;
    if (b >= B) return;

    __shared__ float s_cont[2][16*68];   // content -> later new_fact
    __shared__ float s_scr [2][16*68];   // ante -> later matched
    __shared__ float s_ms  [2][16*20];   // match_scores
    __shared__ float s_sm  [2][96];      // conf@0 pf@16 pr@32 rcn@48 ran@64
    float* cont = s_cont[w];
    float* scr  = s_scr[w];
    float* ms   = s_ms[w];
    float* sm   = s_sm[w];

    const float thr = expf(lft[0]);

    // load content (regs + LDS), conf/types
    float c[16];
    const float* cb = content + ((size_t)b << 10);
    #pragma unroll
    for (int k = 0; k < 16; k++) {
        float v = cb[(k << 6) + l];
        c[k] = v;
        cont[k*68 + l] = v;
    }
    if (l < 16) {
        sm[0  + l] = conf[((size_t)b << 4) + l];
        sm[16 + l] = types[(((size_t)b << 4) + l)*3 + 0];   // p_fact
        sm[32 + l] = types[(((size_t)b << 4) + l)*3 + 1];   // p_rule
    }

    // content inverse norms -> sm[48+k]
    {
        const int k = l & 15, q = l >> 4;
        const v4f* row = (const v4f*)&cont[k*68 + q*16];
        v2f s2 = {0.f, 0.f};
        #pragma unroll
        for (int i = 0; i < 4; i++) { v4f v = row[i]; pk4(s2, v, v); }
        float s = hsum(s2);
        s += __shfl_xor(s, 16, 64);
        s += __shfl_xor(s, 32, 64);
        if (l < 16) sm[48 + l] = rsq_(s);
    }

    // ante = content @ W_ante^T (W row resident in regs as v2f pairs)
    v2f wA[32];
    {
        const v4f* wr = (const v4f*)(W_ante + ((size_t)l << 6));
        #pragma unroll
        for (int i = 0; i < 16; i++) { v4f v = wr[i]; wA[2*i] = v.xy; wA[2*i+1] = v.zw; }
    }
    #pragma unroll
    for (int k = 0; k < 16; k++) {
        const v4f* cr = (const v4f*)&cont[k*68];
        v2f a = {0.f, 0.f};
        #pragma unroll
        for (int i = 0; i < 16; i++) { v4f v = cr[i]; a += v.xy*wA[2*i]; a += v.zw*wA[2*i+1]; }
        scr[k*68 + l] = hsum(a);
    }

    // ante inverse norms -> sm[64+k]
    {
        const int k = l & 15, q = l >> 4;
        const v4f* row = (const v4f*)&scr[k*68 + q*16];
        v2f s2 = {0.f, 0.f};
        #pragma unroll
        for (int i = 0; i < 4; i++) { v4f v = row[i]; pk4(s2, v, v); }
        float s = hsum(s2);
        s += __shfl_xor(s, 16, 64);
        s += __shfl_xor(s, 32, 64);
        if (l < 16) sm[64 + l] = rsq_(s);
    }

    // dots + match_scores: lane -> (k = l&15, 4 j's); sim = dot * ran * rcn * pf
    {
        const int k = l & 15, jg4 = (l >> 4) * 4;
        const v4f* ar = (const v4f*)&scr[k*68];
        const v4f* c0 = (const v4f*)&cont[(jg4+0)*68];
        const v4f* c1 = (const v4f*)&cont[(jg4+1)*68];
        const v4f* c2 = (const v4f*)&cont[(jg4+2)*68];
        const v4f* c3 = (const v4f*)&cont[(jg4+3)*68];
        v2f d0 = {0,0}, d1 = {0,0}, d2 = {0,0}, d3 = {0,0};
        #pragma unroll
        for (int i = 0; i < 16; i++) {
            v4f a = ar[i];
            v4f x0 = c0[i]; d0 += a.xy*x0.xy; d0 += a.zw*x0.zw;
            v4f x1 = c1[i]; d1 += a.xy*x1.xy; d1 += a.zw*x1.zw;
            v4f x2 = c2[i]; d2 += a.xy*x2.xy; d2 += a.zw*x2.zw;
            v4f x3 = c3[i]; d3 += a.xy*x3.xy; d3 += a.zw*x3.zw;
        }
        const float ra = sm[64 + k];
        v4f res;
        res.x = hsum(d0) * ra * sm[48 + jg4+0] * sm[16 + jg4+0];
        res.y = hsum(d1) * ra * sm[48 + jg4+1] * sm[16 + jg4+1];
        res.z = hsum(d2) * ra * sm[48 + jg4+2] * sm[16 + jg4+2];
        res.w = hsum(d3) * ra * sm[48 + jg4+3] * sm[16 + jg4+3];
        *(v4f*)&ms[k*20 + jg4] = res;
    }

    // match_strength -> fire / dconf (lanes 0..15) -> staging + tail
    float dc_l = 0.f;
    if (l < 16) {
        const v4f* mr = (const v4f*)&ms[l*20];
        const v4f* cf = (const v4f*)&sm[0];
        v2f st = {0.f, 0.f};
        #pragma unroll
        for (int i = 0; i < 4; i++) { v4f m4 = mr[i]; v4f f4 = cf[i]; st += m4.xy*f4.xy; st += m4.zw*f4.zw; }
        float str = hsum(st);
        float fire = sm[32 + l] * rcp_(1.0f + __expf(-(str - thr) * 2.0f));
        float dcf  = fire * sm[0 + l];
        out[((size_t)b << 11) + 1024 + l] = fire;
        out[((size_t)b << 11) + 1040 + l] = dcf;
        dc_l = dcf;
    }
    {
        float mv = dc_l;
        mv = fmaxf(mv, __shfl_xor(mv, 1, 64));
        mv = fmaxf(mv, __shfl_xor(mv, 2, 64));
        mv = fmaxf(mv, __shfl_xor(mv, 4, 64));
        mv = fmaxf(mv, __shfl_xor(mv, 8, 64));
        if (l == 0) out[((size_t)B << 11) + b] = mv;
    }

    // matched[k][d] = sum_j ms[k][j] * content[j][d]  (from regs c[])
    float mt[16];
    #pragma unroll
    for (int k = 0; k < 16; k++) {
        const v4f* mr = (const v4f*)&ms[k*20];
        v2f m2 = {0.f, 0.f};
        #pragma unroll
        for (int i = 0; i < 4; i++) {
            v4f m4 = mr[i];
            v2f clo = {c[4*i+0], c[4*i+1]};
            v2f chi = {c[4*i+2], c[4*i+3]};
            m2 += m4.xy*clo; m2 += m4.zw*chi;
        }
        mt[k] = hsum(m2);
    }
    #pragma unroll
    for (int k = 0; k < 16; k++) scr[k*68 + l] = mt[k];   // ante dead -> matched

    // new_fact = content @ W1^T + matched @ W2^T
    float nf[16];
    {
        const v4f* wr = (const v4f*)(W_cons + ((size_t)l << 7));
        #pragma unroll
        for (int i = 0; i < 16; i++) { v4f v = wr[i]; wA[2*i] = v.xy; wA[2*i+1] = v.zw; }
    }
    #pragma unroll
    for (int k = 0; k < 16; k++) {
        const v4f* cr = (const v4f*)&cont[k*68];
        v2f a = {0.f, 0.f};
        #pragma unroll
        for (int i = 0; i < 16; i++) { v4f v = cr[i]; a += v.xy*wA[2*i]; a += v.zw*wA[2*i+1]; }
        nf[k] = hsum(a);
    }
    {
        const v4f* wr = (const v4f*)(W_cons + ((size_t)l << 7) + 64);
        #pragma unroll
        for (int i = 0; i < 16; i++) { v4f v = wr[i]; wA[2*i] = v.xy; wA[2*i+1] = v.zw; }
    }
    #pragma unroll
    for (int k = 0; k < 16; k++) {
        const v4f* mr = (const v4f*)&scr[k*68];
        v2f a = {0.f, 0.f};
        #pragma unroll
        for (int i = 0; i < 16; i++) { v4f v = mr[i]; a += v.xy*wA[2*i]; a += v.zw*wA[2*i+1]; }
        nf[k] += hsum(a);
    }

    // nf -> LDS (for norms) + global staging
    #pragma unroll
    for (int k = 0; k < 16; k++) {
        cont[k*68 + l] = nf[k];
        out[((size_t)b << 11) + (k << 6) + l] = nf[k];
    }

    // 1/||cand|| -> staging
    {
        const int k = l & 15, q = l >> 4;
        const v4f* row = (const v4f*)&cont[k*68 + q*16];
        v2f s2 = {0.f, 0.f};
        #pragma unroll
        for (int i = 0; i < 4; i++) { v4f v = row[i]; pk4(s2, v, v); }
        float s = hsum(s2);
        s += __shfl_xor(s, 16, 64);
        s += __shfl_xor(s, 32, 64);
        if (l < 16) out[((size_t)b << 11) + 1056 + l] = rsq_(s);
    }
}

// ============================ Kernel 2: sequential scan ============================
// 8 batches per block of 512 (1 batch per wave). S register-resident in
// (m = l&31, h = l>>5) lane layout. W1 block-shared in LDS (conflict-free
// transposed v4f), amortized over 8 waves -> 2 blocks/CU = 16 waves/CU.
// Softmax sum/max via DPP (VALU) instead of ds_swizzle shuffles.
__global__ __launch_bounds__(512, 4)
void scan_kernel(const float* __restrict__ Sg,      // [B,32,64]
                 const float* __restrict__ W_gw,    // [64,128]
                 const float* __restrict__ W_gb,    // [64]
                 float* __restrict__ out, int B)
{
    const int t = threadIdx.x;
    const int l = t & 63;
    const int w = t >> 6;                 // wave 0..7
    const int b = (blockIdx.x << 3) + w;  // batch

    __shared__ v4f            w1v[1024];         // block-shared W1: w1v[i*64+j] = W1[j][4i..4i+3]
    __shared__ float          snf_  [8][16*64];  // new_fact rows
    __shared__ unsigned short gcB_  [8][16*64];  // bf16 gamma cand-half [k][l]
    __shared__ float          smeta_[8][48];     // fire[16] dconf[16] 1/||cand||[16]
    __shared__ float          bsb_  [8][68];     // best-slot row (d-layout)
    __shared__ float          ncb_  [8][68];     // new_content (d-layout)
    float* snf   = snf_[w];
    unsigned short* gcB = gcB_[w];
    float* smeta = smeta_[w];
    float* bsb   = bsb_[w];
    float* ncb   = ncb_[w];

    const int m = l & 31, h = l >> 5;

    // -------- block-cooperative W1 -> LDS (transposed v4f layout) --------
    {
        #pragma unroll
        for (int j = 0; j < 2; j++) {
            const int i = (w << 1) + j;          // chunk 0..15
            w1v[i*64 + l] = *(const v4f*)&W_gw[(size_t)l*128 + i*4];
        }
    }

    v2f Sreg[16];

    if (b < B) {
        // meta staging
        if (l < 48) smeta[l] = out[((size_t)b << 11) + 1024 + l];

        // new_fact staging -> LDS (flat b128 copy, coalesced)
        const float* nfb = out + ((size_t)b << 11);
        #pragma unroll
        for (int i = 0; i < 4; i++) {
            *(v4f*)&snf[i*256 + l*4] = *(const v4f*)&nfb[i*256 + l*4];
        }

        // S -> regs in (m,h) layout: lane owns contiguous half-row S[m][32h..32h+32)
        {
            const float* srow = Sg + ((size_t)b << 11) + (m << 6) + (h << 5);
            #pragma unroll
            for (int i = 0; i < 8; i++) {
                v4f v = *(const v4f*)&srow[i*4];
                Sreg[2*i]   = v.xy;
                Sreg[2*i+1] = v.zw;
            }
        }

        // gc[k][l] = cand_k . W_gw[l][64:128]  (wB transient)
        {
            v2f wB[32];
            const v4f* w2 = (const v4f*)(W_gw + ((size_t)l << 7) + 64);
            #pragma unroll
            for (int i = 0; i < 16; i++) { v4f v = w2[i]; wB[2*i] = v.xy; wB[2*i+1] = v.zw; }
            #pragma unroll
            for (int k = 0; k < 16; k++) {
                const v4f* cr = (const v4f*)&snf[k << 6];
                v2f a = {0.f, 0.f};
                #pragma unroll
                for (int i = 0; i < 16; i++) { v4f v = cr[i]; a += v.xy*wB[2*i]; a += v.zw*wB[2*i+1]; }
                const float g = hsum(a);
                gcB[(k << 6) + l] = (unsigned short)((__float_as_uint(g) + 0x8000u) >> 16);
            }
        }
    }

    __syncthreads();          // w1v visible to all waves
    if (b >= B) return;

    const float gb = W_gb[l];

    // ---------------- sequential scan: chain = regs + LDS + DPP ----------------
    #pragma unroll 1
    for (int k = 0; k < 16; k++) {
        const float fire = smeta[k];          // wave-uniform
        if (fire <= 0.1f) continue;
        const float dck  = smeta[16 + k];
        const float rncn = smeta[32 + k];     // 1/||cand||
        const float gck  = __uint_as_float((unsigned)gcB[(k << 6) + l] << 16);
        const float cd   = snf[(k << 6) + l]; // cand[l], per-lane

        // dot[m] = cand.S[m] and ||S[m]||^2 -- registers + broadcast cand
        v2f d2 = {0.f, 0.f}, n2 = {0.f, 0.f};
        {
            const v4f* cr = (const v4f*)&snf[(k << 6) + (h << 5)];
            #pragma unroll
            for (int i = 0; i < 8; i++) {
                v4f c = cr[i];
                d2 += Sreg[2*i]*c.xy;       d2 += Sreg[2*i+1]*c.zw;
                n2 += Sreg[2*i]*Sreg[2*i];  n2 += Sreg[2*i+1]*Sreg[2*i+1];
            }
        }
        float dt = hsum(d2);
        float nn = hsum(n2);
        dt += __shfl_xor(dt, 32, 64);       // combine the two half-rows
        nn += __shfl_xor(nn, 32, 64);
        const float sc = dt * rsq_(nn) * rncn;
        const float e  = __expf(4.0f * sc);

        // argmax via DPP max (uniform) + ballot; first index on ties
        const float mx = dpp_max64(sc);
        const unsigned long long bal = __ballot(sc == mx);
        const int best = __ffsll(bal & 0xffffffffULL) - 1;   // wave-uniform

        // best-slot row -> bsb early (owning 2 lanes write their halves)
        if (m == best) {
            #pragma unroll
            for (int j = 0; j < 8; j++) {
                v4f v = { Sreg[2*j].x, Sreg[2*j].y, Sreg[2*j+1].x, Sreg[2*j+1].y };
                *(v4f*)&bsb[(h << 5) + j*4] = v;
            }
        }

        // softmax sum via DPP (overlaps bsb write); halves duplicated -> x2
        const float tot = dpp_sum64(e);
        const float wm  = dck * e * 2.0f * rcp_(tot);  // this lane's slot weight

        // gamma[l] = sigmoid(bs . W1[l] + gc + gb); W1 from block LDS
        v2f g2 = {0.f, 0.f};
        {
            const v4f* wrow = &w1v[l];
            #pragma unroll
            for (int i = 0; i < 16; i++) {
                v4f bs = *(const v4f*)&bsb[i*4];   // broadcast (same addr all lanes)
                v4f wv = wrow[i*64];               // conflict-free (consecutive lanes)
                g2 += bs.xy*wv.xy; g2 += bs.zw*wv.zw;
            }
        }
        const float g = gb + gck + hsum(g2);
        const float gamma = rcp_(1.0f + __expf(-g));
        const float bsd = bsb[l];                      // per-lane
        ncb[l] = gamma*cd + (1.0f - gamma)*bsd;        // new_content, d-layout

        // update own half-row: S[m][d] += wm * (ncd[d] - S[m][d])
        const v2f wm2 = {wm, wm};
        {
            const v4f* nr = (const v4f*)&ncb[h << 5];
            #pragma unroll
            for (int i = 0; i < 8; i++) {
                v4f nc = nr[i];
                Sreg[2*i]   += wm2 * (nc.xy - Sreg[2*i]);
                Sreg[2*i+1] += wm2 * (nc.zw - Sreg[2*i+1]);
            }
        }
    }

    // store S_new from regs (overwrites staging region)
    {
        float* ob = out + ((size_t)b << 11) + (m << 6) + (h << 5);
        #pragma unroll
        for (int j = 0; j < 8; j++) {
            v4f v = { Sreg[2*j].x, Sreg[2*j].y, Sreg[2*j+1].x, Sreg[2*j+1].y };
            *(v4f*)&ob[j*4] = v;
        }
    }
}

extern "C" void kernel_launch(void* const* d_in, const int* in_sizes, int n_in,
                              void* d_out, int out_size, void* d_ws, size_t ws_size,
                              hipStream_t stream) {
    const float* content = (const float*)d_in[0];
    const float* types   = (const float*)d_in[1];
    const float* conf    = (const float*)d_in[2];
    const float* S       = (const float*)d_in[3];
    const float* W_ante  = (const float*)d_in[4];
    const float* W_cons  = (const float*)d_in[5];
    const float* W_gw    = (const float*)d_in[6];
    const float* W_gb    = (const float*)d_in[7];
    const float* lft     = (const float*)d_in[8];

    const int B = in_sizes[0] / 1024;

    hipLaunchKernelGGL(dense_kernel, dim3((B + 1) / 2), dim3(128), 0, stream,
                       content, types, conf, W_ante, W_cons, lft, (float*)d_out, B);
    hipLaunchKernelGGL(scan_kernel, dim3((B + 7) / 8), dim3(512), 0, stream,
                       S, W_gw, W_gb, (float*)d_out, B);
}